// Round 2
// baseline (1405.845 us; speedup 1.0000x reference)
//
#include <hip/hip_runtime.h>

#define NCAM 6
#define FC   128
#define FH_  32
#define FW_  88
#define NPIX (FH_*FW_)        // 2816
#define ND   41
#define X3C  170              // 41 depth + 1 opacity + 128 feat
#define OUTC 128
#define GTOT (NCAM*NPIX)      // 16896
#define BEVH 100
#define BEVW 100
#define NPXB (BEVH*BEVW)      // 10000
#define NTILE 25              // 25x25 tiles of 4x4 px
#define NWORD 264             // 16896/64 mask words per tile
#define CAP   2048            // LDS hit-list segment size

// ---- ws layout (float offsets) ----
#define WS_CAM    0                          // 6*24 = 144 floats
#define WS_X1     256
#define WS_X2     (WS_X1 + NCAM*FC*NPIX)     // +2162688
#define WS_X3     (WS_X2 + NCAM*FC*NPIX)
#define WS_GAUSS  (WS_X3 + NCAM*X3C*NPIX)
#define WS_COLORS WS_X1                      // X1 dead after conv2; reuse
#define WS_MASKS  WS_X2                      // X2 dead after conv1x1; reuse (1.32 MB)

__device__ inline void inv3x3(const float* m, float* o) {
    float a=m[0],b=m[1],c=m[2],d=m[3],e=m[4],f=m[5],g=m[6],h=m[7],i=m[8];
    float A=e*i-f*h, B=c*h-b*i, C=b*f-c*e;
    float Dd=f*g-d*i, E=a*i-c*g, F=c*d-a*f;
    float Gg=d*h-e*g, H=b*g-a*h, I=a*e-b*d;
    float r = 1.0f/(a*A + b*Dd + c*Gg);
    o[0]=A*r; o[1]=B*r; o[2]=C*r; o[3]=Dd*r; o[4]=E*r; o[5]=F*r;
    o[6]=Gg*r; o[7]=H*r; o[8]=I*r;
}

__global__ void cam_consts_kernel(const float* __restrict__ rot, const float* __restrict__ tr,
                                  const float* __restrict__ intr, const float* __restrict__ prot,
                                  const float* __restrict__ ptr_, float* __restrict__ cam) {
    int n = threadIdx.x;
    if (n >= NCAM) return;
    float M1[9], Ki[9];
    inv3x3(prot + n*9, M1);
    inv3x3(intr + n*9, Ki);
    const float* R = rot + n*9;
    float* c = cam + n*24;
    for (int i=0;i<9;i++) c[i] = M1[i];
    for (int i=0;i<3;i++) c[9+i] = ptr_[n*3+i];
    for (int i=0;i<3;i++)
        for (int j=0;j<3;j++)
            c[12+i*3+j] = R[i*3+0]*Ki[0+j] + R[i*3+1]*Ki[3+j] + R[i*3+2]*Ki[6+j];
    for (int i=0;i<3;i++) c[21+i] = tr[n*3+i];
}

// direct 3x3 conv + folded BN + ReLU. grid (NCAM, 32 co-groups of 4, 4 pixel chunks of 768)
__global__ __launch_bounds__(256) void conv3x3_bn_relu_kernel(
        const float* __restrict__ in, float* __restrict__ out, const float* __restrict__ w,
        const float* __restrict__ cb, const float* __restrict__ bg, const float* __restrict__ bb,
        const float* __restrict__ bm, const float* __restrict__ bv) {
    const int n   = blockIdx.x;
    const int co0 = blockIdx.y * 4;
    const int t   = threadIdx.x;
    const int pbase = blockIdx.z * 768;
    float scale[4], shift[4];
    #pragma unroll
    for (int c=0;c<4;c++) {
        float s = bg[co0+c] * rsqrtf(bv[co0+c] + 1e-3f);
        scale[c] = s;
        shift[c] = (cb[co0+c] - bm[co0+c]) * s + bb[co0+c];
    }
    int hh[3], xx[3];
    #pragma unroll
    for (int k=0;k<3;k++) { int p = pbase + k*256 + t; hh[k] = p/FW_; xx[k] = p - hh[k]*FW_; }
    float acc[4][3] = {};
    const float* ib = in + (size_t)n*FC*NPIX;
    const float* wb = w  + (size_t)co0*FC*9;
    for (int ci=0; ci<FC; ++ci) {
        const float* ip = ib + (size_t)ci*NPIX;
        float wr[4][9];
        #pragma unroll
        for (int c=0;c<4;c++)
            #pragma unroll
            for (int k=0;k<9;k++) wr[c][k] = wb[(size_t)c*FC*9 + ci*9 + k];
        #pragma unroll
        for (int k=0;k<3;k++) {
            float v[9];
            #pragma unroll
            for (int dy=0;dy<3;dy++) {
                int y = hh[k] + dy - 1;
                bool yok = (unsigned)y < (unsigned)FH_;
                #pragma unroll
                for (int dx=0;dx<3;dx++) {
                    int x = xx[k] + dx - 1;
                    v[dy*3+dx] = (yok && (unsigned)x < (unsigned)FW_) ? ip[y*FW_ + x] : 0.0f;
                }
            }
            #pragma unroll
            for (int c=0;c<4;c++) {
                float a = acc[c][k];
                a = fmaf(wr[c][0], v[0], a); a = fmaf(wr[c][1], v[1], a);
                a = fmaf(wr[c][2], v[2], a); a = fmaf(wr[c][3], v[3], a);
                a = fmaf(wr[c][4], v[4], a); a = fmaf(wr[c][5], v[5], a);
                a = fmaf(wr[c][6], v[6], a); a = fmaf(wr[c][7], v[7], a);
                a = fmaf(wr[c][8], v[8], a);
                acc[c][k] = a;
            }
        }
    }
    #pragma unroll
    for (int k=0;k<3;k++) {
        int p = pbase + k*256 + t;
        if (p < NPIX) {
            #pragma unroll
            for (int c=0;c<4;c++)
                out[((size_t)n*FC + co0 + c)*NPIX + p] = fmaxf(fmaf(acc[c][k], scale[c], shift[c]), 0.0f);
        }
    }
}

// 1x1 conv (conv3). grid (NCAM, 43 co-groups of 4, 4 pixel chunks)
__global__ __launch_bounds__(256) void conv1x1_kernel(const float* __restrict__ in,
        float* __restrict__ out, const float* __restrict__ w, const float* __restrict__ b) {
    const int n   = blockIdx.x;
    const int co0 = blockIdx.y * 4;
    const int t   = threadIdx.x;
    const int pbase = blockIdx.z * 768;
    float acc[4][3];
    #pragma unroll
    for (int c=0;c<4;c++) {
        float bias = (co0+c < X3C) ? b[co0+c] : 0.0f;
        #pragma unroll
        for (int k=0;k<3;k++) acc[c][k] = bias;
    }
    const float* ib = in + (size_t)n*FC*NPIX;
    for (int ci=0; ci<FC; ++ci) {
        float wr[4];
        #pragma unroll
        for (int c=0;c<4;c++) wr[c] = (co0+c < X3C) ? w[(size_t)(co0+c)*FC + ci] : 0.0f;
        #pragma unroll
        for (int k=0;k<3;k++) {
            int p = pbase + k*256 + t;
            float v = (p < NPIX) ? ib[(size_t)ci*NPIX + p] : 0.0f;
            #pragma unroll
            for (int c=0;c<4;c++) acc[c][k] = fmaf(wr[c], v, acc[c][k]);
        }
    }
    #pragma unroll
    for (int k=0;k<3;k++) {
        int p = pbase + k*256 + t;
        if (p < NPIX) {
            #pragma unroll
            for (int c=0;c<4;c++)
                if (co0+c < X3C) out[((size_t)n*X3C + co0+c)*NPIX + p] = acc[c][k];
        }
    }
}

// per-gaussian: softmax over depth, xy moments (geometry computed inline),
// splat precompute {my,mx,A,B,C,qm,ri,rj}; count opacity mask.
__global__ __launch_bounds__(256) void moments_kernel(const float* __restrict__ x3,
        const float* __restrict__ cam, float* __restrict__ gauss, float* __restrict__ ng) {
    int gi = blockIdx.x*256 + threadIdx.x;            // 66*256 == 16896 exactly
    int n  = gi / NPIX;
    int p  = gi - n*NPIX;
    int h  = p / FW_, xp = p - h*FW_;
    const float* cc = cam + n*24;
    float u = xp * (703.0f/87.0f);
    float v = h  * (255.0f/31.0f);
    float fx = u - cc[9], fy = v - cc[10], fz = -cc[11];
    float p0x = cc[0]*fx + cc[1]*fy + cc[2]*fz;
    float p0y = cc[3]*fx + cc[4]*fy + cc[5]*fz;
    float p0z = cc[6]*fx + cc[7]*fy + cc[8]*fz;
    const float* lg = x3 + (size_t)n*X3C*NPIX + p;

    float mxl = -1e30f;
    for (int d=0; d<ND; ++d) mxl = fmaxf(mxl, lg[(size_t)d*NPIX]);
    float s=0.f, sgx=0.f, sgy=0.f;
    for (int d=0; d<ND; ++d) {
        float e  = __expf(lg[(size_t)d*NPIX] - mxl);
        float dz = 4.0f + (float)d;
        float pz = p0z + dz*cc[8];
        float px = (p0x + dz*cc[2]) * pz;
        float py = (p0y + dz*cc[5]) * pz;
        float gx = cc[12]*px + cc[13]*py + cc[14]*pz + cc[21];
        float gy = cc[15]*px + cc[16]*py + cc[17]*pz + cc[22];
        s += e; sgx += e*gx; sgy += e*gy;
    }
    float inv_s = 1.0f/s;
    float mex = sgx*inv_s, mey = sgy*inv_s;
    float cxx=0.f, cxy=0.f, cyy=0.f;
    for (int d=0; d<ND; ++d) {
        float e  = __expf(lg[(size_t)d*NPIX] - mxl);
        float dz = 4.0f + (float)d;
        float pz = p0z + dz*cc[8];
        float px = (p0x + dz*cc[2]) * pz;
        float py = (p0y + dz*cc[5]) * pz;
        float gx = cc[12]*px + cc[13]*py + cc[14]*pz + cc[21];
        float gy = cc[15]*px + cc[16]*py + cc[17]*pz + cc[22];
        float dxv = gx - mex, dyv = gy - mey;
        cxx += e*dxv*dxv; cxy += e*dxv*dyv; cyy += e*dyv*dyv;
    }
    const float k9 = inv_s * (1.0f/9.0f);
    cxx *= k9; cxy *= k9; cyy *= k9;

    float lo = lg[(size_t)ND*NPIX];
    float op = 1.0f/(1.0f + __expf(-lo));
    bool mask = op > 0.05f;

    const float SC = 0.02f, SH = 50.0f, SW = 50.0f;
    float my = -SH*(mey*SC) + 50.0f;
    float mx = -SW*(mex*SC) + 50.0f;
    float a  = SH*SH*(cyy*SC*SC) + 0.3f;   // row (i) variance
    float b  = SH*SW*(cxy*SC*SC);
    float c  = SW*SW*(cxx*SC*SC) + 0.3f;   // col (j) variance
    float det = a*c - b*b;
    bool valid = mask && (det > 0.0f);
    float A, Bc, C, qm, ri, rj;
    if (valid) {
        float idet = 1.0f/det;
        A = c*idet; Bc = -b*idet; C = a*idet;
        qm = 2.0f*__logf(255.0f*op);       // alpha>=1/255  <=>  q<=qm  (op>0.05 => qm>5)
        ri = sqrtf(qm*a); rj = sqrtf(qm*c);
    } else { A=Bc=C=0.f; qm=-1.0f; ri=-1e30f; rj=-1e30f; }
    float* gp = gauss + (size_t)gi*8;
    gp[0]=my; gp[1]=mx; gp[2]=A; gp[3]=Bc; gp[4]=C; gp[5]=qm; gp[6]=ri; gp[7]=rj;

    unsigned long long bal = __ballot(mask);
    if ((threadIdx.x & 63) == 0) atomicAdd(ng, (float)__popcll(bal));
}

// x3 feature planes [n][42+c][p]  ->  colors [g][128], LDS-tiled transpose
__global__ __launch_bounds__(256) void transpose_kernel(const float* __restrict__ x3,
                                                        float* __restrict__ colors) {
    __shared__ float lds[128*65];
    const int n  = blockIdx.y;
    const int p0 = blockIdx.x * 64;           // 44 tiles * 64 = 2816
    const int t  = threadIdx.x;
    const int cq = t >> 6, pp = t & 63;
    const float* src = x3 + (size_t)n*X3C*NPIX + (size_t)(ND+1)*NPIX + p0;
    for (int c = cq; c < OUTC; c += 4)
        lds[c*65 + pp] = src[(size_t)c*NPIX + pp];
    __syncthreads();
    for (int it = 0; it < 32; ++it) {
        int idx = it*256 + t;
        int c   = idx & 127;
        int pq  = idx >> 7;
        colors[((size_t)(n*NPIX + p0 + pq) << 7) + c] = lds[c*65 + pq];
    }
}

// bin gaussians to 4x4-px tiles: per (tile, 64-g word) hit bitmask. Order is
// preserved because splat walks words/bits in ascending gaussian index.
__global__ __launch_bounds__(256) void build_masks_kernel(const float* __restrict__ gauss,
        unsigned long long* __restrict__ masks) {
    const int g = blockIdx.x*256 + threadIdx.x;
    const float4 g0 = *(const float4*)(gauss + ((size_t)g << 3));      // my,mx,A,B
    const float4 g1 = *(const float4*)(gauss + ((size_t)g << 3) + 4);  // C,qm,ri,rj
    if (g1.y < 0.0f) return;                   // invalid gaussian
    const float my = g0.x, mx = g0.y, ri = g1.z, rj = g1.w;
    int ti0 = (int)floorf((my - ri) * 0.25f);
    int ti1 = (int)floorf((my + ri) * 0.25f);
    int tj0 = (int)floorf((mx - rj) * 0.25f);
    int tj1 = (int)floorf((mx + rj) * 0.25f);
    ti0 = max(ti0, 0); tj0 = max(tj0, 0);
    ti1 = min(ti1, NTILE-1); tj1 = min(tj1, NTILE-1);
    const int wi = g >> 6;
    const unsigned long long bit = 1ull << (g & 63);
    for (int ti = ti0; ti <= ti1; ++ti)
        for (int tj = tj0; tj <= tj1; ++tj)
            atomicOr(&masks[(size_t)(ti*NTILE + tj)*NWORD + wi], bit);
}

// ordered compositing, one block per 4x4 tile. Extract hit indices from the
// tile's bitmask (ascending order) into LDS, then composite with a 1-deep
// software pipeline. Thread = 4 channels x 2 pixels; colors load coalesced.
__global__ __launch_bounds__(256) void splat_tiles_kernel(const float* __restrict__ gauss,
        const float* __restrict__ colors, const unsigned long long* __restrict__ masks,
        float* __restrict__ out) {
    __shared__ unsigned long long smask[NWORD];
    __shared__ unsigned short list[CAP];
    const int t  = threadIdx.x;
    const int ti = blockIdx.x / NTILE, tj = blockIdx.x % NTILE;
    const int i0 = ti*4, j0 = tj*4;
    const int c4  = (t & 31) << 2;          // channel base (coalesced color loads)
    const int pxq = t >> 5;                 // 0..7 -> pixel pxq (rows 0-1) and pxq+8 (rows 2-3)
    const float fi0 = (float)(i0 + (pxq >> 2));
    const float fj  = (float)(j0 + (pxq & 3));

    const unsigned long long* gm = masks + (size_t)blockIdx.x * NWORD;
    for (int idx = t; idx < NWORD; idx += 256) smask[idx] = gm[idx];
    __syncthreads();

    float T0 = 1.0f, T1 = 1.0f;
    float4 acc0 = make_float4(0.f,0.f,0.f,0.f);
    float4 acc1 = make_float4(0.f,0.f,0.f,0.f);

    int wi = 0;
    unsigned long long cur = smask[0];
    while (wi < NWORD) {
        // ---- extract one segment of hit indices (uniform walk; t0 writes) ----
        int cnt = 0;
        while (wi < NWORD && cnt < CAP) {
            if (cur == 0ull) { ++wi; if (wi < NWORD) cur = smask[wi]; continue; }
            int b = __builtin_ctzll(cur);
            cur &= cur - 1ull;
            if (t == 0) list[cnt] = (unsigned short)((wi << 6) + b);
            ++cnt;
        }
        __syncthreads();
        // ---- composite this segment with 1-deep prefetch ----
        int g = cnt ? (int)list[0] : 0;
        float4 ga = *(const float4*)(gauss + ((size_t)g << 3));
        float4 gb = *(const float4*)(gauss + ((size_t)g << 3) + 4);
        float4 cl = *(const float4*)(colors + ((size_t)g << 7) + c4);
        for (int k = 0; k < cnt; ++k) {
            int gn = (k + 1 < cnt) ? (int)list[k + 1] : g;
            float4 ga_n = *(const float4*)(gauss + ((size_t)gn << 3));
            float4 gb_n = *(const float4*)(gauss + ((size_t)gn << 3) + 4);
            float4 cl_n = *(const float4*)(colors + ((size_t)gn << 7) + c4);
            const float A = ga.z, Bv = ga.w, Cv = gb.x, qm = gb.y;
            const float dJ = fj - ga.y;
            const float cj = Cv * dJ * dJ, bj2 = 2.0f * Bv * dJ;
            {   // pixel pxq (rows 0-1)
                float dI = fi0 - ga.x;
                float q  = dI * (A * dI + bj2) + cj;
                if (q >= 0.0f && q <= qm) {
                    float al = fminf(0.99f, 0.003921568627f * __expf(0.5f * (qm - q)));
                    float w = al * T0; T0 -= w;
                    acc0.x = fmaf(w, cl.x, acc0.x); acc0.y = fmaf(w, cl.y, acc0.y);
                    acc0.z = fmaf(w, cl.z, acc0.z); acc0.w = fmaf(w, cl.w, acc0.w);
                }
            }
            {   // pixel pxq+8 (rows 2-3)
                float dI = fi0 + 2.0f - ga.x;
                float q  = dI * (A * dI + bj2) + cj;
                if (q >= 0.0f && q <= qm) {
                    float al = fminf(0.99f, 0.003921568627f * __expf(0.5f * (qm - q)));
                    float w = al * T1; T1 -= w;
                    acc1.x = fmaf(w, cl.x, acc1.x); acc1.y = fmaf(w, cl.y, acc1.y);
                    acc1.z = fmaf(w, cl.z, acc1.z); acc1.w = fmaf(w, cl.w, acc1.w);
                }
            }
            ga = ga_n; gb = gb_n; cl = cl_n;
        }
        __syncthreads();   // before next segment overwrites list
    }

    const int pix0 = (i0 + (pxq >> 2)) * BEVW + j0 + (pxq & 3);
    const int pix1 = pix0 + 2 * BEVW;
    out[(size_t)(c4+0)*NPXB + pix0] = acc0.x;
    out[(size_t)(c4+1)*NPXB + pix0] = acc0.y;
    out[(size_t)(c4+2)*NPXB + pix0] = acc0.z;
    out[(size_t)(c4+3)*NPXB + pix0] = acc0.w;
    out[(size_t)(c4+0)*NPXB + pix1] = acc1.x;
    out[(size_t)(c4+1)*NPXB + pix1] = acc1.y;
    out[(size_t)(c4+2)*NPXB + pix1] = acc1.z;
    out[(size_t)(c4+3)*NPXB + pix1] = acc1.w;
}

extern "C" void kernel_launch(void* const* d_in, const int* in_sizes, int n_in,
                              void* d_out, int out_size, void* d_ws, size_t ws_size,
                              hipStream_t stream) {
    const float* rot  = (const float*)d_in[0];
    const float* tr   = (const float*)d_in[1];
    const float* intr = (const float*)d_in[2];
    const float* prot = (const float*)d_in[3];
    const float* ptr_ = (const float*)d_in[4];
    const float* img  = (const float*)d_in[5];
    const float* c1w  = (const float*)d_in[6];  const float* c1b = (const float*)d_in[7];
    const float* b1g  = (const float*)d_in[8];  const float* b1b = (const float*)d_in[9];
    const float* b1m  = (const float*)d_in[10]; const float* b1v = (const float*)d_in[11];
    const float* c2w  = (const float*)d_in[12]; const float* c2b = (const float*)d_in[13];
    const float* b2g  = (const float*)d_in[14]; const float* b2b = (const float*)d_in[15];
    const float* b2m  = (const float*)d_in[16]; const float* b2v = (const float*)d_in[17];
    const float* c3w  = (const float*)d_in[18]; const float* c3b = (const float*)d_in[19];
    float* out = (float*)d_out;
    float* ws  = (float*)d_ws;
    float* CAM = ws + WS_CAM;
    float* X1  = ws + WS_X1;
    float* X2  = ws + WS_X2;
    float* X3  = ws + WS_X3;
    float* GS  = ws + WS_GAUSS;
    float* COL = ws + WS_COLORS;
    unsigned long long* MASKS = (unsigned long long*)(ws + WS_MASKS);
    float* ngp = out + (size_t)NPXB*OUTC;     // num_gaussians scalar (output 1)

    cam_consts_kernel<<<1, 64, 0, stream>>>(rot, tr, intr, prot, ptr_, CAM);
    conv3x3_bn_relu_kernel<<<dim3(NCAM,32,4), 256, 0, stream>>>(img, X1, c1w, c1b, b1g, b1b, b1m, b1v);
    conv3x3_bn_relu_kernel<<<dim3(NCAM,32,4), 256, 0, stream>>>(X1, X2, c2w, c2b, b2g, b2b, b2m, b2v);
    conv1x1_kernel<<<dim3(NCAM,43,4), 256, 0, stream>>>(X2, X3, c3w, c3b);
    // X2 is dead now; reuse its space for the tile bitmasks
    hipMemsetAsync(MASKS, 0, (size_t)NTILE*NTILE*NWORD*sizeof(unsigned long long), stream);
    hipMemsetAsync(ngp, 0, sizeof(float), stream);
    moments_kernel<<<GTOT/256, 256, 0, stream>>>(X3, CAM, GS, ngp);
    transpose_kernel<<<dim3(44, NCAM), 256, 0, stream>>>(X3, COL);
    build_masks_kernel<<<GTOT/256, 256, 0, stream>>>(GS, MASKS);
    splat_tiles_kernel<<<NTILE*NTILE, 256, 0, stream>>>(GS, COL, MASKS, out);
}

// Round 3
// 763.553 us; speedup vs baseline: 1.8412x; 1.8412x over previous
//
#include <hip/hip_runtime.h>

#define NCAM 6
#define FC   128
#define FH_  32
#define FW_  88
#define NPIX (FH_*FW_)        // 2816
#define ND   41
#define X3C  170              // 41 depth + 1 opacity + 128 feat
#define OUTC 128
#define GTOT (NCAM*NPIX)      // 16896
#define BEVH 100
#define BEVW 100
#define NPXB (BEVH*BEVW)      // 10000
#define NTILE 25              // 25x25 tiles of 4x4 px
#define NWORD 264             // 16896/64 mask words per tile
#define NSEG  4               // segments per tile (parallel compositing)
#define SEGW  66              // words per segment
#define NCHUNK 17             // ceil(66/4) 4-word chunks per segment

// ---- ws layout (float offsets) ---- (total identical to round 1/2 footprint)
#define WS_CAM    0                          // 6*24 = 144 floats
#define WS_X1     256
#define WS_X2     (WS_X1 + NCAM*FC*NPIX)     // +2162688
#define WS_X3     (WS_X2 + NCAM*FC*NPIX)
#define WS_GAUSS  (WS_X3 + NCAM*X3C*NPIX)
#define WS_COLORS WS_X1                      // X1 dead after conv2; reuse
#define WS_MASKS  WS_X2                      // X2 dead after conv1x1; reuse (1.32 MB)
#define WS_B      (WS_X2 + 400000)           // seg log-sums [625][16][4] = 40000 floats

__device__ inline void inv3x3(const float* m, float* o) {
    float a=m[0],b=m[1],c=m[2],d=m[3],e=m[4],f=m[5],g=m[6],h=m[7],i=m[8];
    float A=e*i-f*h, B=c*h-b*i, C=b*f-c*e;
    float Dd=f*g-d*i, E=a*i-c*g, F=c*d-a*f;
    float Gg=d*h-e*g, H=b*g-a*h, I=a*e-b*d;
    float r = 1.0f/(a*A + b*Dd + c*Gg);
    o[0]=A*r; o[1]=B*r; o[2]=C*r; o[3]=Dd*r; o[4]=E*r; o[5]=F*r;
    o[6]=Gg*r; o[7]=H*r; o[8]=I*r;
}

__global__ void cam_consts_kernel(const float* __restrict__ rot, const float* __restrict__ tr,
                                  const float* __restrict__ intr, const float* __restrict__ prot,
                                  const float* __restrict__ ptr_, float* __restrict__ cam) {
    int n = threadIdx.x;
    if (n >= NCAM) return;
    float M1[9], Ki[9];
    inv3x3(prot + n*9, M1);
    inv3x3(intr + n*9, Ki);
    const float* R = rot + n*9;
    float* c = cam + n*24;
    for (int i=0;i<9;i++) c[i] = M1[i];
    for (int i=0;i<3;i++) c[9+i] = ptr_[n*3+i];
    for (int i=0;i<3;i++)
        for (int j=0;j<3;j++)
            c[12+i*3+j] = R[i*3+0]*Ki[0+j] + R[i*3+1]*Ki[3+j] + R[i*3+2]*Ki[6+j];
    for (int i=0;i<3;i++) c[21+i] = tr[n*3+i];
}

// direct 3x3 conv + folded BN + ReLU. grid (NCAM, 32 co-groups of 4, 4 pixel chunks of 768)
__global__ __launch_bounds__(256) void conv3x3_bn_relu_kernel(
        const float* __restrict__ in, float* __restrict__ out, const float* __restrict__ w,
        const float* __restrict__ cb, const float* __restrict__ bg, const float* __restrict__ bb,
        const float* __restrict__ bm, const float* __restrict__ bv) {
    const int n   = blockIdx.x;
    const int co0 = blockIdx.y * 4;
    const int t   = threadIdx.x;
    const int pbase = blockIdx.z * 768;
    float scale[4], shift[4];
    #pragma unroll
    for (int c=0;c<4;c++) {
        float s = bg[co0+c] * rsqrtf(bv[co0+c] + 1e-3f);
        scale[c] = s;
        shift[c] = (cb[co0+c] - bm[co0+c]) * s + bb[co0+c];
    }
    int hh[3], xx[3];
    #pragma unroll
    for (int k=0;k<3;k++) { int p = pbase + k*256 + t; hh[k] = p/FW_; xx[k] = p - hh[k]*FW_; }
    float acc[4][3] = {};
    const float* ib = in + (size_t)n*FC*NPIX;
    const float* wb = w  + (size_t)co0*FC*9;
    for (int ci=0; ci<FC; ++ci) {
        const float* ip = ib + (size_t)ci*NPIX;
        float wr[4][9];
        #pragma unroll
        for (int c=0;c<4;c++)
            #pragma unroll
            for (int k=0;k<9;k++) wr[c][k] = wb[(size_t)c*FC*9 + ci*9 + k];
        #pragma unroll
        for (int k=0;k<3;k++) {
            float v[9];
            #pragma unroll
            for (int dy=0;dy<3;dy++) {
                int y = hh[k] + dy - 1;
                bool yok = (unsigned)y < (unsigned)FH_;
                #pragma unroll
                for (int dx=0;dx<3;dx++) {
                    int x = xx[k] + dx - 1;
                    v[dy*3+dx] = (yok && (unsigned)x < (unsigned)FW_) ? ip[y*FW_ + x] : 0.0f;
                }
            }
            #pragma unroll
            for (int c=0;c<4;c++) {
                float a = acc[c][k];
                a = fmaf(wr[c][0], v[0], a); a = fmaf(wr[c][1], v[1], a);
                a = fmaf(wr[c][2], v[2], a); a = fmaf(wr[c][3], v[3], a);
                a = fmaf(wr[c][4], v[4], a); a = fmaf(wr[c][5], v[5], a);
                a = fmaf(wr[c][6], v[6], a); a = fmaf(wr[c][7], v[7], a);
                a = fmaf(wr[c][8], v[8], a);
                acc[c][k] = a;
            }
        }
    }
    #pragma unroll
    for (int k=0;k<3;k++) {
        int p = pbase + k*256 + t;
        if (p < NPIX) {
            #pragma unroll
            for (int c=0;c<4;c++)
                out[((size_t)n*FC + co0 + c)*NPIX + p] = fmaxf(fmaf(acc[c][k], scale[c], shift[c]), 0.0f);
        }
    }
}

// 1x1 conv (conv3). grid (NCAM, 43 co-groups of 4, 4 pixel chunks)
__global__ __launch_bounds__(256) void conv1x1_kernel(const float* __restrict__ in,
        float* __restrict__ out, const float* __restrict__ w, const float* __restrict__ b) {
    const int n   = blockIdx.x;
    const int co0 = blockIdx.y * 4;
    const int t   = threadIdx.x;
    const int pbase = blockIdx.z * 768;
    float acc[4][3];
    #pragma unroll
    for (int c=0;c<4;c++) {
        float bias = (co0+c < X3C) ? b[co0+c] : 0.0f;
        #pragma unroll
        for (int k=0;k<3;k++) acc[c][k] = bias;
    }
    const float* ib = in + (size_t)n*FC*NPIX;
    for (int ci=0; ci<FC; ++ci) {
        float wr[4];
        #pragma unroll
        for (int c=0;c<4;c++) wr[c] = (co0+c < X3C) ? w[(size_t)(co0+c)*FC + ci] : 0.0f;
        #pragma unroll
        for (int k=0;k<3;k++) {
            int p = pbase + k*256 + t;
            float v = (p < NPIX) ? ib[(size_t)ci*NPIX + p] : 0.0f;
            #pragma unroll
            for (int c=0;c<4;c++) acc[c][k] = fmaf(wr[c], v, acc[c][k]);
        }
    }
    #pragma unroll
    for (int k=0;k<3;k++) {
        int p = pbase + k*256 + t;
        if (p < NPIX) {
            #pragma unroll
            for (int c=0;c<4;c++)
                if (co0+c < X3C) out[((size_t)n*X3C + co0+c)*NPIX + p] = acc[c][k];
        }
    }
}

// per-gaussian: softmax over depth, xy moments, splat params {my,mx,A,B,C,qm,ri,rj}
__global__ __launch_bounds__(256) void moments_kernel(const float* __restrict__ x3,
        const float* __restrict__ cam, float* __restrict__ gauss, float* __restrict__ ng) {
    int gi = blockIdx.x*256 + threadIdx.x;
    int n  = gi / NPIX;
    int p  = gi - n*NPIX;
    int h  = p / FW_, xp = p - h*FW_;
    const float* cc = cam + n*24;
    float u = xp * (703.0f/87.0f);
    float v = h  * (255.0f/31.0f);
    float fx = u - cc[9], fy = v - cc[10], fz = -cc[11];
    float p0x = cc[0]*fx + cc[1]*fy + cc[2]*fz;
    float p0y = cc[3]*fx + cc[4]*fy + cc[5]*fz;
    float p0z = cc[6]*fx + cc[7]*fy + cc[8]*fz;
    const float* lg = x3 + (size_t)n*X3C*NPIX + p;

    float mxl = -1e30f;
    for (int d=0; d<ND; ++d) mxl = fmaxf(mxl, lg[(size_t)d*NPIX]);
    float s=0.f, sgx=0.f, sgy=0.f;
    for (int d=0; d<ND; ++d) {
        float e  = __expf(lg[(size_t)d*NPIX] - mxl);
        float dz = 4.0f + (float)d;
        float pz = p0z + dz*cc[8];
        float px = (p0x + dz*cc[2]) * pz;
        float py = (p0y + dz*cc[5]) * pz;
        float gx = cc[12]*px + cc[13]*py + cc[14]*pz + cc[21];
        float gy = cc[15]*px + cc[16]*py + cc[17]*pz + cc[22];
        s += e; sgx += e*gx; sgy += e*gy;
    }
    float inv_s = 1.0f/s;
    float mex = sgx*inv_s, mey = sgy*inv_s;
    float cxx=0.f, cxy=0.f, cyy=0.f;
    for (int d=0; d<ND; ++d) {
        float e  = __expf(lg[(size_t)d*NPIX] - mxl);
        float dz = 4.0f + (float)d;
        float pz = p0z + dz*cc[8];
        float px = (p0x + dz*cc[2]) * pz;
        float py = (p0y + dz*cc[5]) * pz;
        float gx = cc[12]*px + cc[13]*py + cc[14]*pz + cc[21];
        float gy = cc[15]*px + cc[16]*py + cc[17]*pz + cc[22];
        float dxv = gx - mex, dyv = gy - mey;
        cxx += e*dxv*dxv; cxy += e*dxv*dyv; cyy += e*dyv*dyv;
    }
    const float k9 = inv_s * (1.0f/9.0f);
    cxx *= k9; cxy *= k9; cyy *= k9;

    float lo = lg[(size_t)ND*NPIX];
    float op = 1.0f/(1.0f + __expf(-lo));
    bool mask = op > 0.05f;

    const float SC = 0.02f, SH = 50.0f, SW = 50.0f;
    float my = -SH*(mey*SC) + 50.0f;
    float mx = -SW*(mex*SC) + 50.0f;
    float a  = SH*SH*(cyy*SC*SC) + 0.3f;
    float b  = SH*SW*(cxy*SC*SC);
    float c  = SW*SW*(cxx*SC*SC) + 0.3f;
    float det = a*c - b*b;
    bool valid = mask && (det > 0.0f);
    float A, Bc, C, qm, ri, rj;
    if (valid) {
        float idet = 1.0f/det;
        A = c*idet; Bc = -b*idet; C = a*idet;
        qm = 2.0f*__logf(255.0f*op);
        ri = sqrtf(qm*a); rj = sqrtf(qm*c);
    } else { A=Bc=C=0.f; qm=-1.0f; ri=-1e30f; rj=-1e30f; }
    float* gp = gauss + (size_t)gi*8;
    gp[0]=my; gp[1]=mx; gp[2]=A; gp[3]=Bc; gp[4]=C; gp[5]=qm; gp[6]=ri; gp[7]=rj;

    unsigned long long bal = __ballot(mask);
    if ((threadIdx.x & 63) == 0) atomicAdd(ng, (float)__popcll(bal));
}

// x3 feature planes [n][42+c][p]  ->  colors [g][128]
__global__ __launch_bounds__(256) void transpose_kernel(const float* __restrict__ x3,
                                                        float* __restrict__ colors) {
    __shared__ float lds[128*65];
    const int n  = blockIdx.y;
    const int p0 = blockIdx.x * 64;
    const int t  = threadIdx.x;
    const int cq = t >> 6, pp = t & 63;
    const float* src = x3 + (size_t)n*X3C*NPIX + (size_t)(ND+1)*NPIX + p0;
    for (int c = cq; c < OUTC; c += 4)
        lds[c*65 + pp] = src[(size_t)c*NPIX + pp];
    __syncthreads();
    for (int it = 0; it < 32; ++it) {
        int idx = it*256 + t;
        int c   = idx & 127;
        int pq  = idx >> 7;
        colors[((size_t)(n*NPIX + p0 + pq) << 7) + c] = lds[c*65 + pq];
    }
}

// bin gaussians into per-tile 64-g-word bitmasks (ascending walk preserves order)
__global__ __launch_bounds__(256) void build_masks_kernel(const float* __restrict__ gauss,
        unsigned long long* __restrict__ masks) {
    const int g = blockIdx.x*256 + threadIdx.x;
    const float4 g0 = *(const float4*)(gauss + ((size_t)g << 3));
    const float4 g1 = *(const float4*)(gauss + ((size_t)g << 3) + 4);
    if (g1.y < 0.0f) return;
    const float my = g0.x, mx = g0.y, ri = g1.z, rj = g1.w;
    int ti0 = (int)floorf((my - ri) * 0.25f);
    int ti1 = (int)floorf((my + ri) * 0.25f);
    int tj0 = (int)floorf((mx - rj) * 0.25f);
    int tj1 = (int)floorf((mx + rj) * 0.25f);
    ti0 = max(ti0, 0); tj0 = max(tj0, 0);
    ti1 = min(ti1, NTILE-1); tj1 = min(tj1, NTILE-1);
    const int wi = g >> 6;
    const unsigned long long bit = 1ull << (g & 63);
    for (int ti = ti0; ti <= ti1; ++ti)
        for (int tj = tj0; tj <= tj1; ++tj)
            atomicOr(&masks[(size_t)(ti*NTILE + tj)*NWORD + wi], bit);
}

__device__ inline float eval_alpha(const float4 g0, const float4 g1, float fi, float fj) {
    float dI = fi - g0.x, dJ = fj - g0.y;
    float q = dI*(g0.z*dI + 2.0f*g0.w*dJ) + g1.x*dJ*dJ;
    if (q < 0.0f || q > g1.y) return 0.0f;
    return fminf(0.99f, 0.003921568627f * __expf(0.5f*(g1.y - q)));
}

// per (tile, segment): S[tile][px][seg] = sum of log(1-alpha) over the segment's hits.
__global__ __launch_bounds__(256) void seg_sums_kernel(const float* __restrict__ gauss,
        const unsigned long long* __restrict__ masks, float* __restrict__ B) {
    const int tile = blockIdx.x, seg = blockIdx.y;
    const int t = threadIdx.x;
    const int i0 = (tile / NTILE) * 4, j0 = (tile % NTILE) * 4;
    float ls[16];
    #pragma unroll
    for (int p=0;p<16;p++) ls[p] = 0.0f;
    const unsigned long long* mrow = masks + (size_t)tile*NWORD + seg*SEGW;
    for (int idx = t; idx < SEGW*4; idx += 256) {
        int w = idx >> 2, part = idx & 3;
        unsigned long long m = mrow[w];
        unsigned int bits = (unsigned int)((m >> (part << 4)) & 0xFFFFull);
        while (bits) {
            int b = __builtin_ctz(bits); bits &= bits - 1;
            int g = ((seg*SEGW + w) << 6) + (part << 4) + b;
            float4 g0 = *(const float4*)(gauss + ((size_t)g << 3));
            float4 g1 = *(const float4*)(gauss + ((size_t)g << 3) + 4);
            #pragma unroll
            for (int p=0;p<16;p++) {
                float al = eval_alpha(g0, g1, (float)(i0 + (p>>2)), (float)(j0 + (p&3)));
                if (al > 0.0f) ls[p] += __logf(1.0f - al);
            }
        }
    }
    __shared__ float sp[256][17];
    #pragma unroll
    for (int p=0;p<16;p++) sp[t][p] = ls[p];
    __syncthreads();
    const int px = t & 15, grp = t >> 4;
    float s2 = 0.0f;
    #pragma unroll
    for (int r=0;r<16;r++) s2 += sp[grp*16 + r][px];
    __shared__ float sp2[16][17];
    sp2[grp][px] = s2;
    __syncthreads();
    if (t < 16) {
        float s3 = 0.0f;
        #pragma unroll
        for (int g2=0;g2<16;g2++) s3 += sp2[g2][t];
        B[(size_t)(tile*16 + t)*NSEG + seg] = s3;
    }
}

// per (tile, segment): ordered compositing of the segment's hits, starting from
// T = exp(sum of earlier segments' log-sums). Partial acc atomicAdd'd into out.
__global__ __launch_bounds__(256) void seg_composite_kernel(const float* __restrict__ gauss,
        const float* __restrict__ colors, const unsigned long long* __restrict__ masks,
        const float* __restrict__ B, float* __restrict__ out) {
    __shared__ unsigned long long s_words[SEGW + 2];
    __shared__ float s_alpha[256][17];
    __shared__ unsigned long long s_hit[16][4];
    __shared__ float sbase[16];
    __shared__ unsigned int s_ne;
    const int tile = blockIdx.x, seg = blockIdx.y;
    const int t = threadIdx.x;
    const int i0 = (tile / NTILE) * 4, j0 = (tile % NTILE) * 4;

    const unsigned long long* mrow = masks + (size_t)tile*NWORD + seg*SEGW;
    if (t < SEGW) s_words[t] = mrow[t];
    if (t >= SEGW && t < SEGW+2) s_words[t] = 0ull;
    if (t < 16) {
        float b = 0.0f;
        for (int s = 0; s < seg; ++s) b += B[(size_t)(tile*16 + t)*NSEG + s];
        sbase[t] = b;
    }
    __syncthreads();
    if (t < 64) {
        bool ne = (t < NCHUNK) &&
                  ((s_words[t*4] | s_words[t*4+1] | s_words[t*4+2] | s_words[t*4+3]) != 0ull);
        unsigned long long bal = __ballot(ne);
        if (t == 0) s_ne = (unsigned int)bal;
    }
    __syncthreads();
    unsigned int nem = s_ne;
    if (nem == 0u) return;

    const int px = t >> 4, cs = t & 15;
    float T = __expf(sbase[px]);
    float4 acc0 = make_float4(0.f,0.f,0.f,0.f);
    float4 acc1 = make_float4(0.f,0.f,0.f,0.f);
    const int wave = t >> 6, lane = t & 63;

    while (nem) {
        int c = __builtin_ctz(nem); nem &= nem - 1;
        // ---- eval: thread t <-> candidate slot (word c*4 + t/64, bit t%64) ----
        int wrel = (c << 2) + wave;
        unsigned long long m = s_words[wrel];
        bool active = (m >> lane) & 1ull;
        float a16[16];
        if (active) {
            int g = ((seg*SEGW + wrel) << 6) + lane;
            float4 g0 = *(const float4*)(gauss + ((size_t)g << 3));
            float4 g1 = *(const float4*)(gauss + ((size_t)g << 3) + 4);
            #pragma unroll
            for (int p=0;p<16;p++)
                a16[p] = eval_alpha(g0, g1, (float)(i0 + (p>>2)), (float)(j0 + (p&3)));
        } else {
            #pragma unroll
            for (int p=0;p<16;p++) a16[p] = 0.0f;
        }
        #pragma unroll
        for (int p=0;p<16;p++) s_alpha[t][p] = a16[p];
        #pragma unroll
        for (int p=0;p<16;p++) {
            unsigned long long bal = __ballot(a16[p] > 0.0f);
            if (lane == 0) s_hit[p][wave] = bal;
        }
        __syncthreads();
        // ---- walk hits in ascending order for pixel px, channels cs*8.. ----
        #pragma unroll
        for (int w2 = 0; w2 < 4; ++w2) {
            unsigned long long hm = s_hit[px][w2];
            const int gbase = ((seg*SEGW + (c << 2) + w2) << 6);
            while (hm) {
                int b = __builtin_ctzll(hm); hm &= hm - 1;
                float al = s_alpha[(w2 << 6) + b][px];
                float wgt = al * T; T -= wgt;
                const float* cp = colors + (((size_t)(gbase + b)) << 7) + (cs << 3);
                float4 c0 = *(const float4*)cp;
                float4 c1 = *(const float4*)(cp + 4);
                acc0.x = fmaf(wgt, c0.x, acc0.x); acc0.y = fmaf(wgt, c0.y, acc0.y);
                acc0.z = fmaf(wgt, c0.z, acc0.z); acc0.w = fmaf(wgt, c0.w, acc0.w);
                acc1.x = fmaf(wgt, c1.x, acc1.x); acc1.y = fmaf(wgt, c1.y, acc1.y);
                acc1.z = fmaf(wgt, c1.z, acc1.z); acc1.w = fmaf(wgt, c1.w, acc1.w);
            }
        }
        __syncthreads();
    }

    const int pixg = (i0 + (px >> 2)) * BEVW + (j0 + (px & 3));
    float* op = out + (size_t)(cs << 3) * NPXB + pixg;
    atomicAdd(op + 0*NPXB, acc0.x); atomicAdd(op + 1*NPXB, acc0.y);
    atomicAdd(op + 2*NPXB, acc0.z); atomicAdd(op + 3*NPXB, acc0.w);
    atomicAdd(op + 4*NPXB, acc1.x); atomicAdd(op + 5*NPXB, acc1.y);
    atomicAdd(op + 6*NPXB, acc1.z); atomicAdd(op + 7*NPXB, acc1.w);
}

extern "C" void kernel_launch(void* const* d_in, const int* in_sizes, int n_in,
                              void* d_out, int out_size, void* d_ws, size_t ws_size,
                              hipStream_t stream) {
    const float* rot  = (const float*)d_in[0];
    const float* tr   = (const float*)d_in[1];
    const float* intr = (const float*)d_in[2];
    const float* prot = (const float*)d_in[3];
    const float* ptr_ = (const float*)d_in[4];
    const float* img  = (const float*)d_in[5];
    const float* c1w  = (const float*)d_in[6];  const float* c1b = (const float*)d_in[7];
    const float* b1g  = (const float*)d_in[8];  const float* b1b = (const float*)d_in[9];
    const float* b1m  = (const float*)d_in[10]; const float* b1v = (const float*)d_in[11];
    const float* c2w  = (const float*)d_in[12]; const float* c2b = (const float*)d_in[13];
    const float* b2g  = (const float*)d_in[14]; const float* b2b = (const float*)d_in[15];
    const float* b2m  = (const float*)d_in[16]; const float* b2v = (const float*)d_in[17];
    const float* c3w  = (const float*)d_in[18]; const float* c3b = (const float*)d_in[19];
    float* out = (float*)d_out;
    float* ws  = (float*)d_ws;
    float* CAM = ws + WS_CAM;
    float* X1  = ws + WS_X1;
    float* X2  = ws + WS_X2;
    float* X3  = ws + WS_X3;
    float* GS  = ws + WS_GAUSS;
    float* COL = ws + WS_COLORS;
    unsigned long long* MASKS = (unsigned long long*)(ws + WS_MASKS);
    float* Bsums = ws + WS_B;
    float* ngp = out + (size_t)NPXB*OUTC;

    cam_consts_kernel<<<1, 64, 0, stream>>>(rot, tr, intr, prot, ptr_, CAM);
    conv3x3_bn_relu_kernel<<<dim3(NCAM,32,4), 256, 0, stream>>>(img, X1, c1w, c1b, b1g, b1b, b1m, b1v);
    conv3x3_bn_relu_kernel<<<dim3(NCAM,32,4), 256, 0, stream>>>(X1, X2, c2w, c2b, b2g, b2b, b2m, b2v);
    conv1x1_kernel<<<dim3(NCAM,43,4), 256, 0, stream>>>(X2, X3, c3w, c3b);
    hipMemsetAsync(MASKS, 0, (size_t)NTILE*NTILE*NWORD*sizeof(unsigned long long), stream);
    hipMemsetAsync(ngp, 0, sizeof(float), stream);
    hipMemsetAsync(out, 0, (size_t)NPXB*OUTC*sizeof(float), stream);
    moments_kernel<<<GTOT/256, 256, 0, stream>>>(X3, CAM, GS, ngp);
    transpose_kernel<<<dim3(44, NCAM), 256, 0, stream>>>(X3, COL);
    build_masks_kernel<<<GTOT/256, 256, 0, stream>>>(GS, MASKS);
    seg_sums_kernel<<<dim3(NTILE*NTILE, NSEG), 256, 0, stream>>>(GS, MASKS, Bsums);
    seg_composite_kernel<<<dim3(NTILE*NTILE, NSEG), 256, 0, stream>>>(GS, COL, MASKS, Bsums, out);
}